// Round 8
// baseline (76.464 us; speedup 1.0000x reference)
//
#include <hip/hip_runtime.h>
#include <hip/hip_bf16.h>

#define NNODES 50000
#define DEG 16
#define NEDGES (NNODES * DEG)
#define IND 512
#define OUTD 128

#define BMR 64          // gemm rows per block
#define NB 64           // nodes per block in edge kernel
#define SROWS 80        // staged h rows per block (NB + DEG)

typedef __attribute__((ext_vector_type(8))) short bf16x8;
typedef __attribute__((ext_vector_type(4))) float f32x4;

static __device__ __forceinline__ unsigned short f2bf(float f) {
    unsigned u = __builtin_bit_cast(unsigned, f);
    u += 0x7fffu + ((u >> 16) & 1u);
    return (unsigned short)(u >> 16);
}

static __device__ __forceinline__ bf16x8 pack8(float4 a, float4 b) {
    union { unsigned u[4]; bf16x8 v; } r;
    r.u[0] = (unsigned)f2bf(a.x) | ((unsigned)f2bf(a.y) << 16);
    r.u[1] = (unsigned)f2bf(a.z) | ((unsigned)f2bf(a.w) << 16);
    r.u[2] = (unsigned)f2bf(b.x) | ((unsigned)f2bf(b.y) << 16);
    r.u[3] = (unsigned)f2bf(b.z) | ((unsigned)f2bf(b.w) << 16);
    return r.v;
}

// ---------------- kernel 0: W [512][128] f32 -> Wt [128][512] bf16 ----------------
__global__ __launch_bounds__(256) void wt_kernel(const float* __restrict__ W,
                                                 unsigned short* __restrict__ Wt) {
    int flat = blockIdx.x * 256 + threadIdx.x;   // 16384 = 128 n * 128 k4
    int n  = flat >> 7;
    int k4 = flat & 127;
    int k0 = k4 * 4;
    unsigned short v0 = f2bf(W[(k0 + 0) * OUTD + n]);
    unsigned short v1 = f2bf(W[(k0 + 1) * OUTD + n]);
    unsigned short v2 = f2bf(W[(k0 + 2) * OUTD + n]);
    unsigned short v3 = f2bf(W[(k0 + 3) * OUTD + n]);
    uint2 o;
    o.x = (unsigned)v0 | ((unsigned)v1 << 16);
    o.y = (unsigned)v2 | ((unsigned)v3 << 16);
    *reinterpret_cast<uint2*>(&Wt[n * IND + k0]) = o;
}

// ---------------- kernel 1: h = x @ W  -- ZERO-CHUNK, pinned B, fixed swizzle ----
// 512 thr (8 waves). Block = 64 rows x 128 cols, FULL K staged once.
// B strip (16 cols x 512 K) -> 16 bf16x8/lane, PINNED in regs (anti-sink).
// A tile: 16 float4/thread batched loads -> pack bf16 -> LDS with swizzle
//   sigma(c, r) = (c & 56) | ((c ^ (c>>3) ^ r) & 7)   [write AND read conflict-free]
// ONE __syncthreads; main loop = pure ds_read_b128 + MFMA.
__global__ __launch_bounds__(512, 2) void gemm_kernel(const float* __restrict__ x,
                                                      const unsigned short* __restrict__ Wt,
                                                      float* __restrict__ h) {
    __shared__ __align__(16) unsigned char Al[65536];   // [64 rows][64 granules x 16B]

    const int tid  = threadIdx.x;
    const int lane = tid & 63;
    const int wid  = tid >> 6;        // 0..7
    const int l15  = lane & 15;
    const int kg   = lane >> 4;       // 0..3
    const int base = blockIdx.x * BMR;
    const int wc   = wid * 16;        // wave's 16-col strip

    // ---- B: issue full-K strip loads (L2-hot Wt), 16 x 16B per lane ----
    const unsigned short* bp = &Wt[(size_t)(wc + l15) * IND + kg * 8];
    bf16x8 bfr[16];
#pragma unroll
    for (int k = 0; k < 16; ++k)
        bfr[k] = *reinterpret_cast<const bf16x8*>(bp + k * 32);

    // ---- A: batch-load 16 float4 (row r, granules t*8..t*8+7), pack, swizzled write ----
    const int r = tid >> 3;
    const int t = tid & 7;
    {
        int gr = base + r; if (gr > NNODES - 1) gr = NNODES - 1;
        const float* gp = &x[(size_t)gr * IND + t * 64];
        float4 va[16];
#pragma unroll
        for (int j = 0; j < 16; ++j)
            va[j] = *reinterpret_cast<const float4*>(gp + j * 4);
        unsigned char* aw = &Al[(size_t)r * 1024];
#pragma unroll
        for (int j = 0; j < 8; ++j) {
            bf16x8 q = pack8(va[2 * j], va[2 * j + 1]);
            int slot = t * 8 + ((j ^ t ^ r) & 7);       // sigma(t*8+j, r)
            *reinterpret_cast<bf16x8*>(aw + slot * 16) = q;
        }
    }
    __syncthreads();

    // ---- pin B fragments: forces loads completed & resident here, not in the loop ----
#pragma unroll
    for (int k = 0; k < 16; ++k)
        asm volatile("" : "+v"(bfr[k]));

    // ---- main sweep: 16 K-steps, LDS + MFMA only ----
    f32x4 acc[4];
#pragma unroll
    for (int mt = 0; mt < 4; ++mt) acc[mt] = (f32x4){0.f, 0.f, 0.f, 0.f};

#pragma unroll
    for (int k = 0; k < 16; ++k) {
        const int s = k * 4 + kg;                       // granule index 0..63
#pragma unroll
        for (int mt = 0; mt < 4; ++mt) {
            int rr   = mt * 16 + l15;
            int slot = (s & 56) | ((s ^ (s >> 3) ^ rr) & 7);
            bf16x8 af = *reinterpret_cast<const bf16x8*>(&Al[(size_t)rr * 1024 + slot * 16]);
            acc[mt] = __builtin_amdgcn_mfma_f32_16x16x32_bf16(af, bfr[k], acc[mt], 0, 0, 0);
        }
    }

    // ---- C write: col = lane&15, row = kg*4 + q (per mt block) ----
#pragma unroll
    for (int mt = 0; mt < 4; ++mt) {
#pragma unroll
        for (int q = 0; q < 4; ++q) {
            int grow = base + mt * 16 + kg * 4 + q;
            if (grow < NNODES)
                h[(size_t)grow * OUTD + wc + l15] = acc[mt][q];
        }
    }
}

// ---------------- kernel 2: scores + segment softmax ----------------
__global__ __launch_bounds__(256) void edge_kernel(const float* __restrict__ h,
                                                   const float* __restrict__ a,
                                                   const int* __restrict__ eidx,
                                                   float* __restrict__ attn) {
    extern __shared__ __align__(16) unsigned char hl[];   // SROWS*512 = 40960 B

    const int tid  = threadIdx.x;
    const int base = blockIdx.x * NB;
    const int lane = tid & 63;
    const int wid  = tid >> 6;
    const int j    = lane >> 2;   // edge slot 0..15
    const int g    = lane & 3;    // dim group 0..3

    float4 a4[8];
#pragma unroll
    for (int c = 0; c < 8; ++c)
        a4[c] = *reinterpret_cast<const float4*>(&a[c * 16 + g * 4]);

    for (int p = 0; p < 10; ++p) {
        int f    = p * 256 + tid;         // 2560 16B-slots
        int row  = f >> 5;
        int blkp = f & 31;
        int blk  = blkp ^ ((row & 7) << 2);
        int gr   = base + row;
        if (gr >= NNODES) gr -= NNODES;
        float4 v = *reinterpret_cast<const float4*>(&h[(size_t)gr * OUTD + blk * 4]);
        *reinterpret_cast<float4*>(&hl[f * 16]) = v;
    }
    __syncthreads();

    const int* cols = eidx + NEDGES;
    for (int n = 0; n < 16; ++n) {
        int i = base + wid * 16 + n;
        if (i >= NNODES) break;           // wave-uniform
        int e   = i * DEG + j;
        int col = cols[e];
        int cr  = col - base;
        if (cr < 0) cr += NNODES;
        int ri = i - base;
        float s = 0.f;
        if (cr < SROWS) {
#pragma unroll
            for (int c = 0; c < 8; ++c) {
                int blk = c * 4 + g;
                float4 hi = *reinterpret_cast<const float4*>(&hl[ri * 512 + ((blk ^ ((ri & 7) << 2)) * 16)]);
                float4 hj = *reinterpret_cast<const float4*>(&hl[cr * 512 + ((blk ^ ((cr & 7) << 2)) * 16)]);
                s = fmaf(fabsf(hi.x - hj.x), a4[c].x, s);
                s = fmaf(fabsf(hi.y - hj.y), a4[c].y, s);
                s = fmaf(fabsf(hi.z - hj.z), a4[c].z, s);
                s = fmaf(fabsf(hi.w - hj.w), a4[c].w, s);
            }
        } else {
#pragma unroll
            for (int c = 0; c < 8; ++c) {
                int blk = c * 4 + g;
                float4 hi = *reinterpret_cast<const float4*>(&hl[ri * 512 + ((blk ^ ((ri & 7) << 2)) * 16)]);
                float4 hj = *reinterpret_cast<const float4*>(&h[(size_t)col * OUTD + blk * 4]);
                s = fmaf(fabsf(hi.x - hj.x), a4[c].x, s);
                s = fmaf(fabsf(hi.y - hj.y), a4[c].y, s);
                s = fmaf(fabsf(hi.z - hj.z), a4[c].z, s);
                s = fmaf(fabsf(hi.w - hj.w), a4[c].w, s);
            }
        }
        s += __shfl_xor(s, 1);
        s += __shfl_xor(s, 2);
        s = fmaxf(s, 0.f);
        float m = s;
        m = fmaxf(m, __shfl_xor(m, 4));
        m = fmaxf(m, __shfl_xor(m, 8));
        m = fmaxf(m, __shfl_xor(m, 16));
        m = fmaxf(m, __shfl_xor(m, 32));
        float pv = __expf(s - m);
        float S = pv;
        S += __shfl_xor(S, 4);
        S += __shfl_xor(S, 8);
        S += __shfl_xor(S, 16);
        S += __shfl_xor(S, 32);
        if (g == 0) attn[e] = pv / S;
    }
}

extern "C" void kernel_launch(void* const* d_in, const int* in_sizes, int n_in,
                              void* d_out, int out_size, void* d_ws, size_t ws_size,
                              hipStream_t stream) {
    const float* x  = (const float*)d_in[0];
    const float* W  = (const float*)d_in[1];
    const float* a  = (const float*)d_in[2];
    const int* eidx = (const int*)d_in[3];
    float* h    = (float*)d_out;
    float* attn = h + (size_t)NNODES * OUTD;
    unsigned short* Wt = (unsigned short*)d_ws;   // 128 KB scratch

    hipLaunchKernelGGL(wt_kernel, dim3(64), dim3(256), 0, stream, W, Wt);
    hipLaunchKernelGGL(gemm_kernel, dim3((NNODES + BMR - 1) / BMR), dim3(512), 0, stream, x, Wt, h);
    hipLaunchKernelGGL(edge_kernel, dim3((NNODES + NB - 1) / NB), dim3(256), SROWS * 512, stream,
                       h, a, eidx, attn);
}

// Round 9
// 61.224 us; speedup vs baseline: 1.2489x; 1.2489x over previous
//
#include <hip/hip_runtime.h>
#include <hip/hip_bf16.h>

#define NNODES 50000
#define DEG 16
#define NEDGES (NNODES * DEG)
#define IND 512
#define OUTD 128

#define BM 64           // gemm rows per block
#define CK 64           // K chunk
#define NCH 8           // 512 / 64
#define NB 64           // nodes per block in edge kernel
#define SROWS 80        // staged h rows per block (NB + DEG)

typedef __attribute__((ext_vector_type(8))) short bf16x8;
typedef __attribute__((ext_vector_type(4))) float f32x4;

static __device__ __forceinline__ unsigned short f2bf(float f) {
    unsigned u = __builtin_bit_cast(unsigned, f);
    u += 0x7fffu + ((u >> 16) & 1u);
    return (unsigned short)(u >> 16);
}

static __device__ __forceinline__ bf16x8 pack8(float4 a, float4 b) {
    union { unsigned u[4]; bf16x8 v; } r;
    r.u[0] = (unsigned)f2bf(a.x) | ((unsigned)f2bf(a.y) << 16);
    r.u[1] = (unsigned)f2bf(a.z) | ((unsigned)f2bf(a.w) << 16);
    r.u[2] = (unsigned)f2bf(b.x) | ((unsigned)f2bf(b.y) << 16);
    r.u[3] = (unsigned)f2bf(b.z) | ((unsigned)f2bf(b.w) << 16);
    return r.v;
}

// ---------------- kernel 0: W [512][128] f32 -> Wt [128][512] bf16 ----------------
__global__ __launch_bounds__(256) void wt_kernel(const float* __restrict__ W,
                                                 unsigned short* __restrict__ Wt) {
    int flat = blockIdx.x * 256 + threadIdx.x;   // 16384 = 128 n * 128 k4
    int n  = flat >> 7;
    int k4 = flat & 127;
    int k0 = k4 * 4;
    unsigned short v0 = f2bf(W[(k0 + 0) * OUTD + n]);
    unsigned short v1 = f2bf(W[(k0 + 1) * OUTD + n]);
    unsigned short v2 = f2bf(W[(k0 + 2) * OUTD + n]);
    unsigned short v3 = f2bf(W[(k0 + 3) * OUTD + n]);
    uint2 o;
    o.x = (unsigned)v0 | ((unsigned)v1 << 16);
    o.y = (unsigned)v2 | ((unsigned)v3 << 16);
    *reinterpret_cast<uint2*>(&Wt[n * IND + k0]) = o;
}

// ---------------- kernel 1: h = x @ W  (bf16 MFMA, f32 accum) ----------------
// R5 champion structure (best measured: 61.3 us total, ~= contention roofline).
// BM=64 x full 128 cols, K chunks of 64, double-buffered LDS via global_load_lds,
// counted s_waitcnt vmcnt(8) + raw s_barrier (prefetch never drains in loop).
// A staged raw f32 (convert on read); B staged bf16 from L2-hot Wt.
// Swizzle rule #21: LDS dest linear, global SOURCE pre-swizzled per 16B granule,
// read applies the same XOR. LDS 64 KB -> 2 blocks/CU.
__global__ __launch_bounds__(256, 2) void gemm_kernel(const float* __restrict__ x,
                                                      const unsigned short* __restrict__ Wt,
                                                      float* __restrict__ h) {
    __shared__ __align__(16) unsigned char lds_[65536];

    const int tid  = threadIdx.x;
    const int lane = tid & 63;
    const int wid  = tid >> 6;
    const int l15  = lane & 15;
    const int kg   = lane >> 4;
    const int base = blockIdx.x * BM;
    const int wr   = wid * 16;        // wave's 16-row slice

    f32x4 acc[8];
#pragma unroll
    for (int nt = 0; nt < 8; ++nt) acc[nt] = (f32x4){0.f, 0.f, 0.f, 0.f};

    // per-chunk staging: 8 gload_lds per thread (4 A granules + 4 B granules)
    auto stage = [&](int buf, int ch) {
        const int k0 = ch * CK;
        // A: 64 rows x 16 granules(16B) = 1024, 4/thread
#pragma unroll
        for (int p = 0; p < 4; ++p) {
            int f   = p * 256 + tid;
            int row = f >> 4;
            int g   = (f & 15) ^ (row & 7);          // pre-swizzled source granule
            int gr  = base + row; if (gr > NNODES - 1) gr = NNODES - 1;
            const float* gp = &x[(size_t)gr * IND + k0 + g * 4];
            unsigned char* lp = &lds_[(size_t)buf * 16384 + (size_t)f * 16];
            __builtin_amdgcn_global_load_lds((const unsigned int*)gp, (unsigned int*)lp, 16, 0, 0);
        }
        // B: 128 cols x 8 granules(16B) = 1024, 4/thread
#pragma unroll
        for (int p = 0; p < 4; ++p) {
            int f   = p * 256 + tid;
            int col = f >> 3;
            int g   = (f & 7) ^ (col & 7);
            const unsigned short* gp = &Wt[(size_t)col * IND + k0 + g * 8];
            unsigned char* lp = &lds_[32768 + (size_t)buf * 16384 + (size_t)f * 16];
            __builtin_amdgcn_global_load_lds((const unsigned int*)gp, (unsigned int*)lp, 16, 0, 0);
        }
    };

    stage(0, 0);

    int buf = 0;
    for (int ch = 0; ch < NCH; ++ch) {
        if (ch < NCH - 1) {
            stage(buf ^ 1, ch + 1);                     // next chunk in flight
            asm volatile("s_waitcnt vmcnt(8)" ::: "memory");   // only chunk-ch done
        } else {
            asm volatile("s_waitcnt vmcnt(0)" ::: "memory");
        }
        __builtin_amdgcn_s_barrier();                   // raw barrier: no vmcnt drain

#pragma unroll
        for (int ks = 0; ks < 2; ++ks) {
            // A frag: row wr+l15, k-granules ks*8+kg*2, +1 (swizzled)
            int arow = wr + l15;
            const unsigned char* ab = &lds_[(size_t)buf * 16384 + (size_t)arow * 256];
            int g0 = (ks * 8 + kg * 2) ^ (arow & 7);
            int g1 = (ks * 8 + kg * 2 + 1) ^ (arow & 7);
            float4 a0 = *reinterpret_cast<const float4*>(ab + g0 * 16);
            float4 a1 = *reinterpret_cast<const float4*>(ab + g1 * 16);
            bf16x8 af = pack8(a0, a1);
#pragma unroll
            for (int nt = 0; nt < 8; ++nt) {
                int col = nt * 16 + l15;
                int gB  = (ks * 4 + kg) ^ (col & 7);
                bf16x8 bv = *reinterpret_cast<const bf16x8*>(
                    &lds_[32768 + (size_t)buf * 16384 + (size_t)col * 128 + gB * 16]);
                acc[nt] = __builtin_amdgcn_mfma_f32_16x16x32_bf16(af, bv, acc[nt], 0, 0, 0);
            }
        }
        __builtin_amdgcn_s_barrier();                   // buf safe to overwrite
        buf ^= 1;
    }

    // C/D layout: col = lane&15, row = (lane>>4)*4 + q
#pragma unroll
    for (int q = 0; q < 4; ++q) {
        int grow = base + wr + kg * 4 + q;
        if (grow < NNODES) {
#pragma unroll
            for (int nt = 0; nt < 8; ++nt)
                h[(size_t)grow * OUTD + nt * 16 + l15] = acc[nt][q];
        }
    }
}

// ---------------- kernel 2: scores + segment softmax ----------------
__global__ __launch_bounds__(256) void edge_kernel(const float* __restrict__ h,
                                                   const float* __restrict__ a,
                                                   const int* __restrict__ eidx,
                                                   float* __restrict__ attn) {
    extern __shared__ __align__(16) unsigned char hl[];   // SROWS*512 = 40960 B

    const int tid  = threadIdx.x;
    const int base = blockIdx.x * NB;
    const int lane = tid & 63;
    const int wid  = tid >> 6;
    const int j    = lane >> 2;   // edge slot 0..15
    const int g    = lane & 3;    // dim group 0..3

    float4 a4[8];
#pragma unroll
    for (int c = 0; c < 8; ++c)
        a4[c] = *reinterpret_cast<const float4*>(&a[c * 16 + g * 4]);

    for (int p = 0; p < 10; ++p) {
        int f    = p * 256 + tid;         // 2560 16B-slots
        int row  = f >> 5;
        int blkp = f & 31;
        int blk  = blkp ^ ((row & 7) << 2);
        int gr   = base + row;
        if (gr >= NNODES) gr -= NNODES;
        float4 v = *reinterpret_cast<const float4*>(&h[(size_t)gr * OUTD + blk * 4]);
        *reinterpret_cast<float4*>(&hl[f * 16]) = v;
    }
    __syncthreads();

    const int* cols = eidx + NEDGES;
    for (int n = 0; n < 16; ++n) {
        int i = base + wid * 16 + n;
        if (i >= NNODES) break;           // wave-uniform
        int e   = i * DEG + j;
        int col = cols[e];
        int cr  = col - base;
        if (cr < 0) cr += NNODES;
        int ri = i - base;
        float s = 0.f;
        if (cr < SROWS) {
#pragma unroll
            for (int c = 0; c < 8; ++c) {
                int blk = c * 4 + g;
                float4 hi = *reinterpret_cast<const float4*>(&hl[ri * 512 + ((blk ^ ((ri & 7) << 2)) * 16)]);
                float4 hj = *reinterpret_cast<const float4*>(&hl[cr * 512 + ((blk ^ ((cr & 7) << 2)) * 16)]);
                s = fmaf(fabsf(hi.x - hj.x), a4[c].x, s);
                s = fmaf(fabsf(hi.y - hj.y), a4[c].y, s);
                s = fmaf(fabsf(hi.z - hj.z), a4[c].z, s);
                s = fmaf(fabsf(hi.w - hj.w), a4[c].w, s);
            }
        } else {
#pragma unroll
            for (int c = 0; c < 8; ++c) {
                int blk = c * 4 + g;
                float4 hi = *reinterpret_cast<const float4*>(&hl[ri * 512 + ((blk ^ ((ri & 7) << 2)) * 16)]);
                float4 hj = *reinterpret_cast<const float4*>(&h[(size_t)col * OUTD + blk * 4]);
                s = fmaf(fabsf(hi.x - hj.x), a4[c].x, s);
                s = fmaf(fabsf(hi.y - hj.y), a4[c].y, s);
                s = fmaf(fabsf(hi.z - hj.z), a4[c].z, s);
                s = fmaf(fabsf(hi.w - hj.w), a4[c].w, s);
            }
        }
        s += __shfl_xor(s, 1);
        s += __shfl_xor(s, 2);
        s = fmaxf(s, 0.f);
        float m = s;
        m = fmaxf(m, __shfl_xor(m, 4));
        m = fmaxf(m, __shfl_xor(m, 8));
        m = fmaxf(m, __shfl_xor(m, 16));
        m = fmaxf(m, __shfl_xor(m, 32));
        float pv = __expf(s - m);
        float S = pv;
        S += __shfl_xor(S, 4);
        S += __shfl_xor(S, 8);
        S += __shfl_xor(S, 16);
        S += __shfl_xor(S, 32);
        if (g == 0) attn[e] = pv / S;
    }
}

extern "C" void kernel_launch(void* const* d_in, const int* in_sizes, int n_in,
                              void* d_out, int out_size, void* d_ws, size_t ws_size,
                              hipStream_t stream) {
    const float* x  = (const float*)d_in[0];
    const float* W  = (const float*)d_in[1];
    const float* a  = (const float*)d_in[2];
    const int* eidx = (const int*)d_in[3];
    float* h    = (float*)d_out;
    float* attn = h + (size_t)NNODES * OUTD;
    unsigned short* Wt = (unsigned short*)d_ws;   // 128 KB scratch

    hipLaunchKernelGGL(wt_kernel, dim3(64), dim3(256), 0, stream, W, Wt);
    hipLaunchKernelGGL(gemm_kernel, dim3((NNODES + BM - 1) / BM), dim3(256), 0, stream, x, Wt, h);
    hipLaunchKernelGGL(edge_kernel, dim3((NNODES + NB - 1) / NB), dim3(256), SROWS * 512, stream,
                       h, a, eidx, attn);
}